// Round 1
// baseline (247.353 us; speedup 1.0000x reference)
//
#include <hip/hip_runtime.h>

// SpMM: out[b,m] = bias[m] + sum_{e: dst[e]==m} values[e] * x[b, src[e]]
// B=32, N=M=50000, E=1600000.
// Strategy: transpose x to (N,32) so each edge's batch vector is one 128B line;
// accumulate into out_t (M,32) with coalesced atomics; transpose back + bias.

#define BATCH 32

// ---- kernel 1: x (B,N) -> xt (N,B), LDS tiled ----
__global__ void k_transpose_x(const float* __restrict__ x, float* __restrict__ xt, int N) {
    __shared__ float tile[32][33];
    const int n0 = blockIdx.x * 32;
    const int tx = threadIdx.x;   // 0..31
    const int ty = threadIdx.y;   // 0..7
    // load: coalesced along n (tx)
    #pragma unroll
    for (int k = 0; k < 4; ++k) {
        const int b = ty + 8 * k;
        const int n = n0 + tx;
        tile[tx][b] = (n < N) ? x[(size_t)b * N + n] : 0.0f;
    }
    __syncthreads();
    // store: coalesced along b (tx)
    #pragma unroll
    for (int k = 0; k < 4; ++k) {
        const int n = n0 + ty + 8 * k;
        if (n < N) xt[(size_t)n * BATCH + tx] = tile[ty + 8 * k][tx];
    }
}

// ---- kernel 2: out_t[m*32+b] = bias[m] ----
__global__ void k_init_out_t(const float* __restrict__ bias, float* __restrict__ out_t, int M) {
    const int i = blockIdx.x * blockDim.x + threadIdx.x;
    if (i < M * BATCH) {
        out_t[i] = bias[i >> 5];
    }
}

// ---- kernel 3: per-(edge,batch) coalesced gather + atomic scatter ----
__global__ void k_scatter(const float* __restrict__ xt, const float* __restrict__ values,
                          const int* __restrict__ idx, float* __restrict__ out_t, int E) {
    const int t = blockIdx.x * blockDim.x + threadIdx.x;
    const int e = t >> 5;      // edge
    const int b = t & 31;      // batch
    if (e < E) {
        const int src = idx[e];        // first row of (2,E)
        const int dst = idx[E + e];    // second row
        const float v = values[e];
        const float contrib = v * xt[(size_t)src * BATCH + b];
        atomicAdd(&out_t[(size_t)dst * BATCH + b], contrib);
    }
}

// ---- kernel 4: out_t (M,32) -> out (32,M), LDS tiled ----
__global__ void k_transpose_out(const float* __restrict__ out_t, float* __restrict__ out, int M) {
    __shared__ float tile[32][33];
    const int m0 = blockIdx.x * 32;
    const int tx = threadIdx.x;   // 0..31
    const int ty = threadIdx.y;   // 0..7
    // load: coalesced along b (tx)
    #pragma unroll
    for (int k = 0; k < 4; ++k) {
        const int m = m0 + ty + 8 * k;
        if (m < M) tile[ty + 8 * k][tx] = out_t[(size_t)m * BATCH + tx];
    }
    __syncthreads();
    // store: coalesced along m (tx)
    #pragma unroll
    for (int k = 0; k < 4; ++k) {
        const int b = ty + 8 * k;
        const int m = m0 + tx;
        if (m < M) out[(size_t)b * M + m] = tile[tx][b];
    }
}

extern "C" void kernel_launch(void* const* d_in, const int* in_sizes, int n_in,
                              void* d_out, int out_size, void* d_ws, size_t ws_size,
                              hipStream_t stream) {
    const float* x      = (const float*)d_in[0];  // (B,N,1) fp32
    const float* values = (const float*)d_in[1];  // (E,)    fp32
    const float* bias   = (const float*)d_in[2];  // (M,1)   fp32
    const int*   idx    = (const int*)d_in[3];    // (2,E)   int32

    const int N = in_sizes[0] / BATCH;   // 50000
    const int E = in_sizes[3] / 2;       // 1600000
    const int M = in_sizes[2];           // 50000

    float* out   = (float*)d_out;
    float* xt    = (float*)d_ws;                         // N*32 floats = 6.4 MB
    float* out_t = xt + (size_t)N * BATCH;               // M*32 floats = 6.4 MB

    dim3 tblk(32, 8);

    k_transpose_x<<<(N + 31) / 32, tblk, 0, stream>>>(x, xt, N);
    k_init_out_t<<<(M * BATCH + 255) / 256, 256, 0, stream>>>(bias, out_t, M);

    const long long total = (long long)E * BATCH;
    k_scatter<<<(int)((total + 255) / 256), 256, 0, stream>>>(xt, values, idx, out_t, E);

    k_transpose_out<<<(M + 31) / 32, tblk, 0, stream>>>(out_t, out, M);
}